// Round 19
// baseline (155.011 us; speedup 1.0000x reference)
//
#include <hip/hip_runtime.h>
#include <hip/hip_bf16.h>
#include <stdint.h>

// ---- types ----
typedef __attribute__((ext_vector_type(4))) float  f32x4a;   // MFMA acc
typedef __attribute__((ext_vector_type(8))) short  bf16x8s;  // MFMA A/B frag (8 bf16)
typedef __attribute__((ext_vector_type(8))) unsigned short u16x8;

#define QSCALE 0.18033688011112042f   // 0.125 * log2(e): scores in log2 domain

static __device__ __forceinline__ unsigned short f2bf(float f) {
    union { float f; uint32_t u; } v; v.f = f;
    uint32_t u = v.u;
    return (unsigned short)((u + 0x7FFFu + ((u >> 16) & 1u)) >> 16);
}

static __device__ __forceinline__ unsigned int pack2bf(float lo, float hi) {
    __hip_bfloat162 t = __float22bfloat162_rn(make_float2(lo, hi));  // .x -> low 16
    union { __hip_bfloat162 b; unsigned int u; } c; c.b = t;
    return c.u;
}

static __device__ __forceinline__ float exp2a(float x) {
    float r;
    asm("v_exp_f32 %0, %1" : "=v"(r) : "v"(x));
    return r;
}

#define GLL(src, dst)                                                          \
    __builtin_amdgcn_global_load_lds(                                          \
        (const __attribute__((address_space(1))) void*)(src),                  \
        (__attribute__((address_space(3))) void*)(dst), 16, 0, 0)

// ---- x fp32 -> bf16 ----
__global__ __launch_bounds__(256) void k_cvt_bf16(const float* __restrict__ in,
                                                  unsigned short* __restrict__ out, int n8) {
    int i = blockIdx.x * blockDim.x + threadIdx.x;
    if (i >= n8) return;
    const float4* p = (const float4*)(in + (size_t)i * 8);
    float4 a = p[0], b = p[1];
    u16x8 o;
    o[0] = f2bf(a.x); o[1] = f2bf(a.y); o[2] = f2bf(a.z); o[3] = f2bf(a.w);
    o[4] = f2bf(b.x); o[5] = f2bf(b.y); o[6] = f2bf(b.z); o[7] = f2bf(b.w);
    *(u16x8*)(out + (size_t)i * 8) = o;
}

// ---- W [K][N] fp32 -> Wt [N][K] bf16, cols n < nscale multiplied by sc ----
__global__ __launch_bounds__(256) void k_transpose_w(const float* __restrict__ W,
                                                     unsigned short* __restrict__ Wt,
                                                     int K, int N, float sc, int nscale) {
    __shared__ float tile[64][68];
    int bx = blockIdx.x;
    int ntn = N >> 6;
    int kt = bx / ntn, nt = bx % ntn;
    int t = threadIdx.x;
    int r0 = t >> 4;
    int c4 = (t & 15) << 2;
    for (int i = 0; i < 4; ++i) {
        int k = r0 + i * 16;
        float4 v = *(const float4*)(W + (size_t)(kt * 64 + k) * N + nt * 64 + c4);
        tile[k][c4 + 0] = v.x; tile[k][c4 + 1] = v.y;
        tile[k][c4 + 2] = v.z; tile[k][c4 + 3] = v.w;
    }
    __syncthreads();
    int nl = t >> 2;
    int kc = (t & 3) << 4;
    float s = (nt * 64 + nl < nscale) ? sc : 1.0f;
    unsigned short* dst = Wt + (size_t)(nt * 64 + nl) * K + kt * 64 + kc;
    u16x8 o0, o1;
    for (int i = 0; i < 8; ++i) o0[i] = f2bf(tile[kc + i][nl] * s);
    for (int i = 0; i < 8; ++i) o1[i] = f2bf(tile[kc + 8 + i][nl] * s);
    *(u16x8*)dst = o0;
    *(u16x8*)(dst + 8) = o1;
}

// ---- BT GEMM (round-15 proven config): 128x256 tile, BK=32, 3-deep circular
// LDS buffer, 72KB -> 2 blocks/CU, counted vmcnt(3) pipeline.
// QS=1: bias cols < 1024 scaled by QSCALE in the epilogue.
// VW=1: tiles with nt>=8 (V third of qkv) write transposed into vt[bh][d][s].
template<int OUT_BF16, int VW, int QS>
__global__ __launch_bounds__(512, 4) void k_gemm2b(const unsigned short* __restrict__ A,
                                                   const unsigned short* __restrict__ Bt,
                                                   const float* __restrict__ bias,
                                                   void* __restrict__ Cout,
                                                   unsigned short* __restrict__ vt,
                                                   int M, int N, int K, int ntn) {
    __shared__ __align__(16) unsigned short S[3][12288];   // [buf][A 4096 | B 8192]
    unsigned short* Sf = &S[0][0];

    int nwg = gridDim.x;
    int bid = blockIdx.x;
    int wg = (bid & 7) * (nwg >> 3) + (bid >> 3);   // bijective XCD swizzle (nwg%8==0)
    int mt = wg / ntn, nt = wg % ntn;
    size_t m0 = (size_t)mt * 128, n0 = (size_t)nt * 256;

    int tid = threadIdx.x;
    int w = tid >> 6, lane = tid & 63;
    int wm = w >> 2, wn = w & 3;                    // 2M x 4N wave grid
    int l15 = lane & 15, l4 = lane >> 4;

    int srow = tid >> 2;
    int sch = (tid & 3) ^ ((srow >> 1) & 3);
    const unsigned short* Asrc = A  + (m0 + srow) * (size_t)K + sch * 8;
    const unsigned short* Bsrc = Bt + (n0 + srow) * (size_t)K + sch * 8;

#define STG(bufoff, kt)                                                                   \
    do {                                                                                  \
        GLL(Asrc + (size_t)(kt) * 32,                    Sf + (bufoff) + tid * 8);        \
        GLL(Bsrc + (size_t)(kt) * 32,                    Sf + (bufoff) + 4096 + tid * 8); \
        GLL(Bsrc + (size_t)(kt) * 32 + (size_t)128 * K,  Sf + (bufoff) + 8192 + tid * 8); \
    } while (0)

    int ck = (l4 ^ ((l15 >> 1) & 3)) * 8;
    int aoff = (wm * 64 + l15) * 32 + ck;
    int boff = 4096 + (wn * 64 + l15) * 32 + ck;

    f32x4a acc[4][4] = {};

#define BAR() __builtin_amdgcn_s_barrier()

    int NT = K >> 5;

    STG(0, 0);
    STG(12288, 1);
    asm volatile("s_waitcnt vmcnt(3)" ::: "memory");
    __builtin_amdgcn_sched_barrier(0);
    BAR();

    int cb = 0;
    for (int t = 0; t < NT; ++t) {
        int sb = cb + 24576; if (sb >= 36864) sb -= 36864;
        bool more = (t + 2) < NT;
        if (more) STG(sb, t + 2);
        bf16x8s af[4], bf[4];
        #pragma unroll
        for (int q = 0; q < 4; ++q) af[q] = *(const bf16x8s*)(Sf + cb + aoff + q * 512);
        #pragma unroll
        for (int q = 0; q < 4; ++q) bf[q] = *(const bf16x8s*)(Sf + cb + boff + q * 512);
        #pragma unroll
        for (int mf = 0; mf < 4; ++mf)
            #pragma unroll
            for (int nf = 0; nf < 4; ++nf)
                acc[mf][nf] = __builtin_amdgcn_mfma_f32_16x16x32_bf16(af[mf], bf[nf],
                                                                      acc[mf][nf], 0, 0, 0);
        if (more) { asm volatile("s_waitcnt vmcnt(3)" ::: "memory"); }
        else      { asm volatile("s_waitcnt vmcnt(0)" ::: "memory"); }
        __builtin_amdgcn_sched_barrier(0);
        BAR();
        cb += 12288; if (cb >= 36864) cb = 0;
    }

    if (VW && nt >= 8) {
        int b = (int)(m0 >> 11);
        int sb_ = ((int)m0 & 2047) + wm * 64;
        #pragma unroll
        for (int nf = 0; nf < 4; ++nf) {
            int vc = ((int)n0 - 2048) + wn * 64 + nf * 16 + l15;
            int h = vc >> 6, d = vc & 63;
            float bv = bias[2048 + vc];
            unsigned short* vrow = vt + ((size_t)(b * 16 + h) * 64 + d) * 2048;
            #pragma unroll
            for (int mf = 0; mf < 4; ++mf) {
                int s = sb_ + mf * 16 + l4 * 4;
                uint2 pv = make_uint2(pack2bf(acc[mf][nf][0] + bv, acc[mf][nf][1] + bv),
                                      pack2bf(acc[mf][nf][2] + bv, acc[mf][nf][3] + bv));
                *(uint2*)(vrow + s) = pv;
            }
        }
    } else {
        #pragma unroll
        for (int nf = 0; nf < 4; ++nf) {
            int col = (int)n0 + wn * 64 + nf * 16 + l15;
            float bv = bias[col];
            if (QS && col < 1024) bv *= QSCALE;
            #pragma unroll
            for (int mf = 0; mf < 4; ++mf) {
                int rbase = (int)m0 + wm * 64 + mf * 16 + l4 * 4;
                #pragma unroll
                for (int rr = 0; rr < 4; ++rr) {
                    float v = acc[mf][nf][rr] + bv;
                    if (OUT_BF16)
                        ((unsigned short*)Cout)[(size_t)(rbase + rr) * N + col] = f2bf(v);
                    else
                        ((float*)Cout)[(size_t)(rbase + rr) * N + col] = v;
                }
            }
        }
    }
#undef STG
#undef BAR
}

// ---- small-tile GEMM for proj: 128x128 tile, 256 threads (4 waves 2Mx2N,
// per-wave 64x64 — same per-wave body as k_gemm2b), BK=32, 3-deep circular
// buffer at 16KB/buf = 48KB LDS -> 2-3 blocks/CU. 512 blocks (= >=2/CU,
// tail-free) gives proj the cross-block overlap it lacked at 1 block/CU.
// fp32 out + bias. Counted vmcnt(4) (4 GLL per tile).
__global__ __launch_bounds__(256, 4) void k_gemm_sm(const unsigned short* __restrict__ A,
                                                    const unsigned short* __restrict__ Bt,
                                                    const float* __restrict__ bias,
                                                    float* __restrict__ Cout,
                                                    int M, int N, int K, int ntn) {
    __shared__ __align__(16) unsigned short S[3][8192];   // [buf][A 4096 | B 4096]
    unsigned short* Sf = &S[0][0];

    int nwg = gridDim.x;
    int bid = blockIdx.x;
    int wg = (bid & 7) * (nwg >> 3) + (bid >> 3);   // bijective XCD swizzle (nwg%8==0)
    int mt = wg / ntn, nt = wg % ntn;
    size_t m0 = (size_t)mt * 128, n0 = (size_t)nt * 128;

    int tid = threadIdx.x;
    int w = tid >> 6, lane = tid & 63;
    int wm = w >> 1, wn = w & 1;                    // 2M x 2N wave grid
    int l15 = lane & 15, l4 = lane >> 4;

    int srow = tid >> 2;                            // 0..63
    int sch = (tid & 3) ^ ((srow >> 1) & 3);
    const unsigned short* Asrc = A  + (m0 + srow) * (size_t)K + sch * 8;
    const unsigned short* Bsrc = Bt + (n0 + srow) * (size_t)K + sch * 8;

#define STGS(bufoff, kt)                                                                  \
    do {                                                                                  \
        GLL(Asrc + (size_t)(kt) * 32,                   Sf + (bufoff) + tid * 8);         \
        GLL(Asrc + (size_t)(kt) * 32 + (size_t)64 * K,  Sf + (bufoff) + 2048 + tid * 8);  \
        GLL(Bsrc + (size_t)(kt) * 32,                   Sf + (bufoff) + 4096 + tid * 8);  \
        GLL(Bsrc + (size_t)(kt) * 32 + (size_t)64 * K,  Sf + (bufoff) + 6144 + tid * 8);  \
    } while (0)

    int ck = (l4 ^ ((l15 >> 1) & 3)) * 8;
    int aoff = (wm * 64 + l15) * 32 + ck;
    int boff = 4096 + (wn * 64 + l15) * 32 + ck;

    f32x4a acc[4][4] = {};

    int NT = K >> 5;

    STGS(0, 0);
    STGS(8192, 1);
    asm volatile("s_waitcnt vmcnt(4)" ::: "memory");
    __builtin_amdgcn_sched_barrier(0);
    __builtin_amdgcn_s_barrier();

    int cb = 0;
    for (int t = 0; t < NT; ++t) {
        int sb = cb + 16384; if (sb >= 24576) sb -= 24576;
        bool more = (t + 2) < NT;
        if (more) STGS(sb, t + 2);
        bf16x8s af[4], bf[4];
        #pragma unroll
        for (int q = 0; q < 4; ++q) af[q] = *(const bf16x8s*)(Sf + cb + aoff + q * 512);
        #pragma unroll
        for (int q = 0; q < 4; ++q) bf[q] = *(const bf16x8s*)(Sf + cb + boff + q * 512);
        #pragma unroll
        for (int mf = 0; mf < 4; ++mf)
            #pragma unroll
            for (int nf = 0; nf < 4; ++nf)
                acc[mf][nf] = __builtin_amdgcn_mfma_f32_16x16x32_bf16(af[mf], bf[nf],
                                                                      acc[mf][nf], 0, 0, 0);
        if (more) { asm volatile("s_waitcnt vmcnt(4)" ::: "memory"); }
        else      { asm volatile("s_waitcnt vmcnt(0)" ::: "memory"); }
        __builtin_amdgcn_sched_barrier(0);
        __builtin_amdgcn_s_barrier();
        cb += 8192; if (cb >= 24576) cb = 0;
    }

    #pragma unroll
    for (int nf = 0; nf < 4; ++nf) {
        int col = (int)n0 + wn * 64 + nf * 16 + l15;
        float bv = bias[col];
        #pragma unroll
        for (int mf = 0; mf < 4; ++mf) {
            int rbase = (int)m0 + wm * 64 + mf * 16 + l4 * 4;
            #pragma unroll
            for (int rr = 0; rr < 4; ++rr)
                Cout[(size_t)(rbase + rr) * N + col] = acc[mf][nf][rr] + bv;
        }
    }
#undef STGS
}

// ---- causal flash attention v10 (round-15 proven config) ----
__global__ __launch_bounds__(256, 2) void k_attn(const unsigned short* __restrict__ qkv,
                                                 const unsigned short* __restrict__ vt,
                                                 unsigned short* __restrict__ ctx) {
    __shared__ unsigned short Ks[2][8192];   // [buf][128 kv x 64 d]
    __shared__ unsigned short Vs[2][8192];   // [buf][64 d x 128 kv]
    __shared__ unsigned short Pb[4][2048];   // per-wave [32 rows][64], swizzled
    int bx = blockIdx.x;
    int bh = bx & 63;
    int pr = bx >> 6;                        // 0..7
    int b = bh >> 4, hd = bh & 15;
    int tid = threadIdx.x;
    int w = tid >> 6, lane = tid & 63;
    int l15 = lane & 15, l4 = lane >> 4;

    const unsigned short* Qb  = qkv + (size_t)b * 2048 * 3072 + hd * 64;
    const unsigned short* Kb  = Qb + 1024;
    const unsigned short* Vtb = vt + (size_t)bh * 64 * 2048;

    int kr = tid >> 3, kc = tid & 7;
    const unsigned short* Ksr = Kb + (size_t)kr * 3072 + ((kc ^ (kr & 7)) << 3);
    int vr = tid >> 4, vc = tid & 15;
    const unsigned short* Vsr = Vtb + (size_t)vr * 2048 + ((vc ^ (vr & 7)) << 3);
    unsigned short* pbw = &Pb[w][0];

    int psw  = l15 & 7;
    int ph   = (l4 & 1) * 4;
    int pc0  = ((0 + (l4 >> 1)) ^ psw) * 8;
    int pc1  = ((2 + (l4 >> 1)) ^ psw) * 8;
    int pc2  = ((4 + (l4 >> 1)) ^ psw) * 8;
    int pc3  = ((6 + (l4 >> 1)) ^ psw) * 8;
    int pr0  = ((0 + l4) ^ psw) * 8;
    int pr1  = ((4 + l4) ^ psw) * 8;
    int prow0 = l15 * 64;
    int prow1 = (l15 + 16) * 64;

    bf16x8s onesf;
    #pragma unroll
    for (int i = 0; i < 8; ++i) onesf[i] = (short)0x3F80;

#define STAGE(buf, kv0s)                                                                 \
    do {                                                                                 \
        _Pragma("unroll")                                                                \
        for (int i_ = 0; i_ < 4; ++i_)                                                   \
            GLL(Ksr + (size_t)((kv0s) + 32 * i_) * 3072,                                 \
                &Ks[buf][i_ * 2048 + w * 512]);                                          \
        _Pragma("unroll")                                                                \
        for (int i_ = 0; i_ < 4; ++i_)                                                   \
            GLL(Vsr + (size_t)(16 * i_) * 2048 + (kv0s),                                 \
                &Vs[buf][i_ * 2048 + w * 512]);                                          \
    } while (0)

    for (int half = 0; half < 2; ++half) {
        int j = half ? (15 - pr) : pr;
        int q0 = j * 128 + w * 32;
        int qa0 = q0 + l15, qa1 = q0 + 16 + l15;
        bf16x8s qf[2][2];
        {
            const unsigned short* p0 = Qb + (size_t)(q0 + l15) * 3072 + l4 * 8;
            qf[0][0] = *(const bf16x8s*)p0;
            qf[0][1] = *(const bf16x8s*)(p0 + 32);
            const unsigned short* p1 = p0 + (size_t)16 * 3072;
            qf[1][0] = *(const bf16x8s*)p1;
            qf[1][1] = *(const bf16x8s*)(p1 + 32);
        }
        f32x4a o[2][4] = {};
        f32x4a lsum[2] = {};
        const int NT128 = j + 1;

        STAGE(0, 0);
        asm volatile("s_waitcnt vmcnt(0)" ::: "memory");
        __builtin_amdgcn_sched_barrier(0);
        __builtin_amdgcn_s_barrier();

        for (int t = 0; t < NT128; ++t) {
            int cur = t & 1;
            if (t + 1 < NT128) STAGE(cur ^ 1, (t + 1) * 128);

            const unsigned short* Kbuf = Ks[cur];
            const unsigned short* Vbuf = Vs[cur];

            #pragma unroll
            for (int hh2 = 0; hh2 < 2; ++hh2) {
                int kvh = t * 128 + hh2 * 64;
                if (kvh > q0 + 31) continue;

                bf16x8s vf[2][4];
                #pragma unroll
                for (int g = 0; g < 2; ++g)
                    #pragma unroll
                    for (int nf = 0; nf < 4; ++nf) {
                        int rv = nf * 16 + l15;
                        int c  = hh2 * 8 + g * 4 + l4;
                        vf[g][nf] = *(const bf16x8s*)(Vbuf + rv * 128 + ((c ^ (rv & 7)) << 3));
                    }

                f32x4a z[2][4];
                __builtin_amdgcn_s_setprio(1);
                #pragma unroll
                for (int f = 0; f < 4; ++f) {
                    int rk = hh2 * 64 + f * 16 + l15;
                    bf16x8s ka = *(const bf16x8s*)(Kbuf + rk * 64 + ((l4 ^ psw) << 3));
                    bf16x8s kb = *(const bf16x8s*)(Kbuf + rk * 64 + (((4 + l4) ^ psw) << 3));
                    #pragma unroll
                    for (int g = 0; g < 2; ++g) {
                        f32x4a zz = {0.f, 0.f, 0.f, 0.f};
                        zz = __builtin_amdgcn_mfma_f32_16x16x32_bf16(ka, qf[g][0], zz, 0, 0, 0);
                        zz = __builtin_amdgcn_mfma_f32_16x16x32_bf16(kb, qf[g][1], zz, 0, 0, 0);
                        z[g][f] = zz;
                    }
                }
                __builtin_amdgcn_s_setprio(0);

                if (kvh + 63 > q0) {
                    #pragma unroll
                    for (int f = 0; f < 4; ++f)
                        #pragma unroll
                        for (int r = 0; r < 4; ++r) {
                            int kvp = kvh + f * 16 + l4 * 4 + r;
                            if (kvp > qa0) z[0][f][r] = -1e30f;
                            if (kvp > qa1) z[1][f][r] = -1e30f;
                        }
                }

                f32x4a p4[2][4];
                #pragma unroll
                for (int g = 0; g < 2; ++g)
                    #pragma unroll
                    for (int f = 0; f < 4; ++f)
                        #pragma unroll
                        for (int r = 0; r < 4; ++r)
                            p4[g][f][r] = exp2a(z[g][f][r]);

                unsigned int pk[2][8];
                #pragma unroll
                for (int g = 0; g < 2; ++g)
                    #pragma unroll
                    for (int f = 0; f < 4; ++f) {
                        pk[g][2 * f]     = pack2bf(p4[g][f][0], p4[g][f][1]);
                        pk[g][2 * f + 1] = pack2bf(p4[g][f][2], p4[g][f][3]);
                    }

                *(uint2*)(pbw + prow0 + pc0 + ph) = make_uint2(pk[0][0], pk[0][1]);
                *(uint2*)(pbw + prow0 + pc1 + ph) = make_uint2(pk[0][2], pk[0][3]);
                *(uint2*)(pbw + prow0 + pc2 + ph) = make_uint2(pk[0][4], pk[0][5]);
                *(uint2*)(pbw + prow0 + pc3 + ph) = make_uint2(pk[0][6], pk[0][7]);
                *(uint2*)(pbw + prow1 + pc0 + ph) = make_uint2(pk[1][0], pk[1][1]);
                *(uint2*)(pbw + prow1 + pc1 + ph) = make_uint2(pk[1][2], pk[1][3]);
                *(uint2*)(pbw + prow1 + pc2 + ph) = make_uint2(pk[1][4], pk[1][5]);
                *(uint2*)(pbw + prow1 + pc3 + ph) = make_uint2(pk[1][6], pk[1][7]);
                asm volatile("" ::: "memory");
                bf16x8s pa[2][2];
                pa[0][0] = *(const bf16x8s*)(pbw + prow0 + pr0);
                pa[0][1] = *(const bf16x8s*)(pbw + prow0 + pr1);
                pa[1][0] = *(const bf16x8s*)(pbw + prow1 + pr0);
                pa[1][1] = *(const bf16x8s*)(pbw + prow1 + pr1);
                asm volatile("" ::: "memory");

                __builtin_amdgcn_s_setprio(1);
                #pragma unroll
                for (int hh = 0; hh < 2; ++hh)
                    #pragma unroll
                    for (int g = 0; g < 2; ++g) {
                        #pragma unroll
                        for (int nf = 0; nf < 4; ++nf)
                            o[g][nf] = __builtin_amdgcn_mfma_f32_16x16x32_bf16(
                                pa[g][hh], vf[hh][nf], o[g][nf], 0, 0, 0);
                        lsum[g] = __builtin_amdgcn_mfma_f32_16x16x32_bf16(
                            pa[g][hh], onesf, lsum[g], 0, 0, 0);
                    }
                __builtin_amdgcn_s_setprio(0);
            }

            asm volatile("s_waitcnt vmcnt(0)" ::: "memory");
            __builtin_amdgcn_sched_barrier(0);
            __builtin_amdgcn_s_barrier();
        }
        __syncthreads();

        float linv0[4], linv1[4];
        #pragma unroll
        for (int r = 0; r < 4; ++r) {
            linv0[r] = 1.0f / lsum[0][r];
            linv1[r] = 1.0f / lsum[1][r];
        }
        #pragma unroll
        for (int nf = 0; nf < 4; ++nf) {
            int col = hd * 64 + nf * 16 + l15;
            #pragma unroll
            for (int r = 0; r < 4; ++r) {
                int row0 = q0 + l4 * 4 + r;
                ctx[((size_t)b * 2048 + row0) * 1024 + col]      = f2bf(o[0][nf][r] * linv0[r]);
                ctx[((size_t)b * 2048 + row0 + 16) * 1024 + col] = f2bf(o[1][nf][r] * linv1[r]);
            }
        }
    }
#undef STAGE
}

extern "C" void kernel_launch(void* const* d_in, const int* in_sizes, int n_in,
                              void* d_out, int out_size, void* d_ws, size_t ws_size,
                              hipStream_t stream) {
    const float* x      = (const float*)d_in[0];
    const float* W_attn = (const float*)d_in[1];
    const float* b_attn = (const float*)d_in[2];
    const float* W_proj = (const float*)d_in[3];
    const float* b_proj = (const float*)d_in[4];

    char* ws = (char*)d_ws;
    unsigned short* xb  = (unsigned short*)ws; ws += (size_t)8192 * 1024 * 2;
    unsigned short* wta = (unsigned short*)ws; ws += (size_t)3072 * 1024 * 2;
    unsigned short* wtp = (unsigned short*)ws; ws += (size_t)1024 * 1024 * 2;
    unsigned short* qkv = (unsigned short*)ws; ws += (size_t)8192 * 3072 * 2;
    unsigned short* vt  = (unsigned short*)ws; ws += (size_t)64 * 64 * 2048 * 2;
    unsigned short* ctx = (unsigned short*)ws;

    k_cvt_bf16<<<4096, 256, 0, stream>>>(x, xb, 8192 * 1024 / 8);
    k_transpose_w<<<16 * 48, 256, 0, stream>>>(W_attn, wta, 1024, 3072, QSCALE, 1024);
    k_transpose_w<<<16 * 16, 256, 0, stream>>>(W_proj, wtp, 1024, 1024, 1.0f, 0);
    k_gemm2b<1, 1, 1><<<768, 512, 0, stream>>>(xb, wta, b_attn, (void*)qkv, vt, 8192, 3072, 1024, 12);
    k_attn<<<512, 256, 0, stream>>>(qkv, vt, ctx);
    k_gemm_sm<<<512, 256, 0, stream>>>(ctx, wtp, b_proj, (float*)d_out, 8192, 1024, 1024, 8);
}

// Round 20
// 152.802 us; speedup vs baseline: 1.0145x; 1.0145x over previous
//
#include <hip/hip_runtime.h>
#include <hip/hip_bf16.h>
#include <stdint.h>

// ---- types ----
typedef __attribute__((ext_vector_type(4))) float  f32x4a;   // MFMA acc
typedef __attribute__((ext_vector_type(8))) short  bf16x8s;  // MFMA A/B frag (8 bf16)
typedef __attribute__((ext_vector_type(8))) unsigned short u16x8;

#define QSCALE 0.18033688011112042f   // 0.125 * log2(e): scores in log2 domain

static __device__ __forceinline__ unsigned short f2bf(float f) {
    union { float f; uint32_t u; } v; v.f = f;
    uint32_t u = v.u;
    return (unsigned short)((u + 0x7FFFu + ((u >> 16) & 1u)) >> 16);
}

static __device__ __forceinline__ unsigned int pack2bf(float lo, float hi) {
    __hip_bfloat162 t = __float22bfloat162_rn(make_float2(lo, hi));  // .x -> low 16
    union { __hip_bfloat162 b; unsigned int u; } c; c.b = t;
    return c.u;
}

static __device__ __forceinline__ float exp2a(float x) {
    float r;
    asm("v_exp_f32 %0, %1" : "=v"(r) : "v"(x));
    return r;
}

#define GLL(src, dst)                                                          \
    __builtin_amdgcn_global_load_lds(                                          \
        (const __attribute__((address_space(1))) void*)(src),                  \
        (__attribute__((address_space(3))) void*)(dst), 16, 0, 0)

// ---- x fp32 -> bf16 ----
__global__ __launch_bounds__(256) void k_cvt_bf16(const float* __restrict__ in,
                                                  unsigned short* __restrict__ out, int n8) {
    int i = blockIdx.x * blockDim.x + threadIdx.x;
    if (i >= n8) return;
    const float4* p = (const float4*)(in + (size_t)i * 8);
    float4 a = p[0], b = p[1];
    u16x8 o;
    o[0] = f2bf(a.x); o[1] = f2bf(a.y); o[2] = f2bf(a.z); o[3] = f2bf(a.w);
    o[4] = f2bf(b.x); o[5] = f2bf(b.y); o[6] = f2bf(b.z); o[7] = f2bf(b.w);
    *(u16x8*)(out + (size_t)i * 8) = o;
}

// ---- W [K][N] fp32 -> Wt [N][K] bf16, cols n < nscale multiplied by sc ----
__global__ __launch_bounds__(256) void k_transpose_w(const float* __restrict__ W,
                                                     unsigned short* __restrict__ Wt,
                                                     int K, int N, float sc, int nscale) {
    __shared__ float tile[64][68];
    int bx = blockIdx.x;
    int ntn = N >> 6;
    int kt = bx / ntn, nt = bx % ntn;
    int t = threadIdx.x;
    int r0 = t >> 4;
    int c4 = (t & 15) << 2;
    for (int i = 0; i < 4; ++i) {
        int k = r0 + i * 16;
        float4 v = *(const float4*)(W + (size_t)(kt * 64 + k) * N + nt * 64 + c4);
        tile[k][c4 + 0] = v.x; tile[k][c4 + 1] = v.y;
        tile[k][c4 + 2] = v.z; tile[k][c4 + 3] = v.w;
    }
    __syncthreads();
    int nl = t >> 2;
    int kc = (t & 3) << 4;
    float s = (nt * 64 + nl < nscale) ? sc : 1.0f;
    unsigned short* dst = Wt + (size_t)(nt * 64 + nl) * K + kt * 64 + kc;
    u16x8 o0, o1;
    for (int i = 0; i < 8; ++i) o0[i] = f2bf(tile[kc + i][nl] * s);
    for (int i = 0; i < 8; ++i) o1[i] = f2bf(tile[kc + 8 + i][nl] * s);
    *(u16x8*)dst = o0;
    *(u16x8*)(dst + 8) = o1;
}

// ---- BT GEMM (round-15/18 proven config): 128x256 tile, BK=32, 3-deep
// circular LDS buffer, 72KB -> 2 blocks/CU, counted vmcnt(3) pipeline.
// QS=1: bias cols < 1024 scaled by QSCALE in the epilogue.
// VW=1: tiles with nt>=8 (V third of qkv) write transposed into vt[bh][d][s].
template<int OUT_BF16, int VW, int QS>
__global__ __launch_bounds__(512, 4) void k_gemm2b(const unsigned short* __restrict__ A,
                                                   const unsigned short* __restrict__ Bt,
                                                   const float* __restrict__ bias,
                                                   void* __restrict__ Cout,
                                                   unsigned short* __restrict__ vt,
                                                   int M, int N, int K, int ntn) {
    __shared__ __align__(16) unsigned short S[3][12288];   // [buf][A 4096 | B 8192]
    unsigned short* Sf = &S[0][0];

    int nwg = gridDim.x;
    int bid = blockIdx.x;
    int wg = (bid & 7) * (nwg >> 3) + (bid >> 3);   // bijective XCD swizzle (nwg%8==0)
    int mt = wg / ntn, nt = wg % ntn;
    size_t m0 = (size_t)mt * 128, n0 = (size_t)nt * 256;

    int tid = threadIdx.x;
    int w = tid >> 6, lane = tid & 63;
    int wm = w >> 2, wn = w & 3;                    // 2M x 4N wave grid
    int l15 = lane & 15, l4 = lane >> 4;

    int srow = tid >> 2;
    int sch = (tid & 3) ^ ((srow >> 1) & 3);
    const unsigned short* Asrc = A  + (m0 + srow) * (size_t)K + sch * 8;
    const unsigned short* Bsrc = Bt + (n0 + srow) * (size_t)K + sch * 8;

#define STG(bufoff, kt)                                                                   \
    do {                                                                                  \
        GLL(Asrc + (size_t)(kt) * 32,                    Sf + (bufoff) + tid * 8);        \
        GLL(Bsrc + (size_t)(kt) * 32,                    Sf + (bufoff) + 4096 + tid * 8); \
        GLL(Bsrc + (size_t)(kt) * 32 + (size_t)128 * K,  Sf + (bufoff) + 8192 + tid * 8); \
    } while (0)

    int ck = (l4 ^ ((l15 >> 1) & 3)) * 8;
    int aoff = (wm * 64 + l15) * 32 + ck;
    int boff = 4096 + (wn * 64 + l15) * 32 + ck;

    f32x4a acc[4][4] = {};

#define BAR() __builtin_amdgcn_s_barrier()

    int NT = K >> 5;

    STG(0, 0);
    STG(12288, 1);
    asm volatile("s_waitcnt vmcnt(3)" ::: "memory");
    __builtin_amdgcn_sched_barrier(0);
    BAR();

    int cb = 0;
    for (int t = 0; t < NT; ++t) {
        int sb = cb + 24576; if (sb >= 36864) sb -= 36864;
        bool more = (t + 2) < NT;
        if (more) STG(sb, t + 2);
        bf16x8s af[4], bf[4];
        #pragma unroll
        for (int q = 0; q < 4; ++q) af[q] = *(const bf16x8s*)(Sf + cb + aoff + q * 512);
        #pragma unroll
        for (int q = 0; q < 4; ++q) bf[q] = *(const bf16x8s*)(Sf + cb + boff + q * 512);
        #pragma unroll
        for (int mf = 0; mf < 4; ++mf)
            #pragma unroll
            for (int nf = 0; nf < 4; ++nf)
                acc[mf][nf] = __builtin_amdgcn_mfma_f32_16x16x32_bf16(af[mf], bf[nf],
                                                                      acc[mf][nf], 0, 0, 0);
        if (more) { asm volatile("s_waitcnt vmcnt(3)" ::: "memory"); }
        else      { asm volatile("s_waitcnt vmcnt(0)" ::: "memory"); }
        __builtin_amdgcn_sched_barrier(0);
        BAR();
        cb += 12288; if (cb >= 36864) cb = 0;
    }

    if (VW && nt >= 8) {
        int b = (int)(m0 >> 11);
        int sb_ = ((int)m0 & 2047) + wm * 64;
        #pragma unroll
        for (int nf = 0; nf < 4; ++nf) {
            int vc = ((int)n0 - 2048) + wn * 64 + nf * 16 + l15;
            int h = vc >> 6, d = vc & 63;
            float bv = bias[2048 + vc];
            unsigned short* vrow = vt + ((size_t)(b * 16 + h) * 64 + d) * 2048;
            #pragma unroll
            for (int mf = 0; mf < 4; ++mf) {
                int s = sb_ + mf * 16 + l4 * 4;
                uint2 pv = make_uint2(pack2bf(acc[mf][nf][0] + bv, acc[mf][nf][1] + bv),
                                      pack2bf(acc[mf][nf][2] + bv, acc[mf][nf][3] + bv));
                *(uint2*)(vrow + s) = pv;
            }
        }
    } else {
        #pragma unroll
        for (int nf = 0; nf < 4; ++nf) {
            int col = (int)n0 + wn * 64 + nf * 16 + l15;
            float bv = bias[col];
            if (QS && col < 1024) bv *= QSCALE;
            #pragma unroll
            for (int mf = 0; mf < 4; ++mf) {
                int rbase = (int)m0 + wm * 64 + mf * 16 + l4 * 4;
                #pragma unroll
                for (int rr = 0; rr < 4; ++rr) {
                    float v = acc[mf][nf][rr] + bv;
                    if (OUT_BF16)
                        ((unsigned short*)Cout)[(size_t)(rbase + rr) * N + col] = f2bf(v);
                    else
                        ((float*)Cout)[(size_t)(rbase + rr) * N + col] = v;
                }
            }
        }
    }
#undef STG
#undef BAR
}

// ---- causal flash attention v11 ----
// = v10 with the two paired q-tiles (jA = pr, jB = 15-pr) merged into ONE kv
// sweep: block sweeps kv tiles 0..jB once; at each 64-kv half the unchanged
// v10 body runs for tile B (guard kvh <= q0B+31) and for tile A when its
// guard admits (kvh <= q0A+31, which subsumes t <= jA). Compute per block
// stays exactly 17 body-executions (balanced); stage+barrier rendezvous drop
// 17 -> 16-pr (avg 12.5) and K/V staging bytes drop ~40%. Bodies run
// sequentially sharing the staged tile; Pb reused with same-wave fences.
__global__ __launch_bounds__(256, 2) void k_attn(const unsigned short* __restrict__ qkv,
                                                 const unsigned short* __restrict__ vt,
                                                 unsigned short* __restrict__ ctx) {
    __shared__ unsigned short Ks[2][8192];   // [buf][128 kv x 64 d]
    __shared__ unsigned short Vs[2][8192];   // [buf][64 d x 128 kv]
    __shared__ unsigned short Pb[4][2048];   // per-wave [32 rows][64], swizzled
    int bx = blockIdx.x;
    int bh = bx & 63;
    int pr = bx >> 6;                        // 0..7
    int b = bh >> 4, hd = bh & 15;
    int tid = threadIdx.x;
    int w = tid >> 6, lane = tid & 63;
    int l15 = lane & 15, l4 = lane >> 4;

    const unsigned short* Qb  = qkv + (size_t)b * 2048 * 3072 + hd * 64;
    const unsigned short* Kb  = Qb + 1024;
    const unsigned short* Vtb = vt + (size_t)bh * 64 * 2048;

    int kr = tid >> 3, kc = tid & 7;
    const unsigned short* Ksr = Kb + (size_t)kr * 3072 + ((kc ^ (kr & 7)) << 3);
    int vr = tid >> 4, vc = tid & 15;
    const unsigned short* Vsr = Vtb + (size_t)vr * 2048 + ((vc ^ (vr & 7)) << 3);
    unsigned short* pbw = &Pb[w][0];

    int psw  = l15 & 7;
    int ph   = (l4 & 1) * 4;
    int pc0  = ((0 + (l4 >> 1)) ^ psw) * 8;
    int pc1  = ((2 + (l4 >> 1)) ^ psw) * 8;
    int pc2  = ((4 + (l4 >> 1)) ^ psw) * 8;
    int pc3  = ((6 + (l4 >> 1)) ^ psw) * 8;
    int pr0  = ((0 + l4) ^ psw) * 8;
    int pr1  = ((4 + l4) ^ psw) * 8;
    int prow0 = l15 * 64;
    int prow1 = (l15 + 16) * 64;

    bf16x8s onesf;
    #pragma unroll
    for (int i = 0; i < 8; ++i) onesf[i] = (short)0x3F80;

#define STAGE(buf, kv0s)                                                                 \
    do {                                                                                 \
        _Pragma("unroll")                                                                \
        for (int i_ = 0; i_ < 4; ++i_)                                                   \
            GLL(Ksr + (size_t)((kv0s) + 32 * i_) * 3072,                                 \
                &Ks[buf][i_ * 2048 + w * 512]);                                          \
        _Pragma("unroll")                                                                \
        for (int i_ = 0; i_ < 4; ++i_)                                                   \
            GLL(Vsr + (size_t)(16 * i_) * 2048 + (kv0s),                                 \
                &Vs[buf][i_ * 2048 + w * 512]);                                          \
    } while (0)

    int jA = pr, jB = 15 - pr;
    int q0A = jA * 128 + w * 32, q0B = jB * 128 + w * 32;
    int qa0A = q0A + l15, qa1A = q0A + 16 + l15;
    int qa0B = q0B + l15, qa1B = q0B + 16 + l15;

    bf16x8s qfA[2][2], qfB[2][2];
    {
        const unsigned short* pA0 = Qb + (size_t)(q0A + l15) * 3072 + l4 * 8;
        qfA[0][0] = *(const bf16x8s*)pA0;
        qfA[0][1] = *(const bf16x8s*)(pA0 + 32);
        const unsigned short* pA1 = pA0 + (size_t)16 * 3072;
        qfA[1][0] = *(const bf16x8s*)pA1;
        qfA[1][1] = *(const bf16x8s*)(pA1 + 32);
        const unsigned short* pB0 = Qb + (size_t)(q0B + l15) * 3072 + l4 * 8;
        qfB[0][0] = *(const bf16x8s*)pB0;
        qfB[0][1] = *(const bf16x8s*)(pB0 + 32);
        const unsigned short* pB1 = pB0 + (size_t)16 * 3072;
        qfB[1][0] = *(const bf16x8s*)pB1;
        qfB[1][1] = *(const bf16x8s*)(pB1 + 32);
    }
    f32x4a oA[2][4] = {}, oB[2][4] = {};
    f32x4a lsA[2] = {}, lsB[2] = {};
    const int NT128 = jB + 1;

    // one v10 step body, parameterized over the q-tile's state
#define BODY(QF, O, LS, Q0, QA0, QA1, kvh, hh2, Kbuf, Vbuf)                              \
    do {                                                                                 \
        bf16x8s vf[2][4];                                                                \
        _Pragma("unroll")                                                                \
        for (int g = 0; g < 2; ++g)                                                      \
            _Pragma("unroll")                                                            \
            for (int nf = 0; nf < 4; ++nf) {                                             \
                int rv = nf * 16 + l15;                                                  \
                int c  = (hh2) * 8 + g * 4 + l4;                                         \
                vf[g][nf] = *(const bf16x8s*)((Vbuf) + rv * 128 + ((c ^ (rv & 7)) << 3));\
            }                                                                            \
        f32x4a z[2][4];                                                                  \
        __builtin_amdgcn_s_setprio(1);                                                   \
        _Pragma("unroll")                                                                \
        for (int f = 0; f < 4; ++f) {                                                    \
            int rk = (hh2) * 64 + f * 16 + l15;                                          \
            bf16x8s ka = *(const bf16x8s*)((Kbuf) + rk * 64 + ((l4 ^ psw) << 3));        \
            bf16x8s kb = *(const bf16x8s*)((Kbuf) + rk * 64 + (((4 + l4) ^ psw) << 3));  \
            _Pragma("unroll")                                                            \
            for (int g = 0; g < 2; ++g) {                                                \
                f32x4a zz = {0.f, 0.f, 0.f, 0.f};                                        \
                zz = __builtin_amdgcn_mfma_f32_16x16x32_bf16(ka, QF[g][0], zz, 0, 0, 0); \
                zz = __builtin_amdgcn_mfma_f32_16x16x32_bf16(kb, QF[g][1], zz, 0, 0, 0); \
                z[g][f] = zz;                                                            \
            }                                                                            \
        }                                                                                \
        __builtin_amdgcn_s_setprio(0);                                                   \
        if ((kvh) + 63 > (Q0)) {                                                         \
            _Pragma("unroll")                                                            \
            for (int f = 0; f < 4; ++f)                                                  \
                _Pragma("unroll")                                                        \
                for (int r = 0; r < 4; ++r) {                                            \
                    int kvp = (kvh) + f * 16 + l4 * 4 + r;                               \
                    if (kvp > (QA0)) z[0][f][r] = -1e30f;                                \
                    if (kvp > (QA1)) z[1][f][r] = -1e30f;                                \
                }                                                                        \
        }                                                                                \
        f32x4a p4[2][4];                                                                 \
        _Pragma("unroll")                                                                \
        for (int g = 0; g < 2; ++g)                                                      \
            _Pragma("unroll")                                                            \
            for (int f = 0; f < 4; ++f)                                                  \
                _Pragma("unroll")                                                        \
                for (int r = 0; r < 4; ++r)                                              \
                    p4[g][f][r] = exp2a(z[g][f][r]);                                     \
        unsigned int pk[2][8];                                                           \
        _Pragma("unroll")                                                                \
        for (int g = 0; g < 2; ++g)                                                      \
            _Pragma("unroll")                                                            \
            for (int f = 0; f < 4; ++f) {                                                \
                pk[g][2 * f]     = pack2bf(p4[g][f][0], p4[g][f][1]);                    \
                pk[g][2 * f + 1] = pack2bf(p4[g][f][2], p4[g][f][3]);                    \
            }                                                                            \
        *(uint2*)(pbw + prow0 + pc0 + ph) = make_uint2(pk[0][0], pk[0][1]);              \
        *(uint2*)(pbw + prow0 + pc1 + ph) = make_uint2(pk[0][2], pk[0][3]);              \
        *(uint2*)(pbw + prow0 + pc2 + ph) = make_uint2(pk[0][4], pk[0][5]);              \
        *(uint2*)(pbw + prow0 + pc3 + ph) = make_uint2(pk[0][6], pk[0][7]);              \
        *(uint2*)(pbw + prow1 + pc0 + ph) = make_uint2(pk[1][0], pk[1][1]);              \
        *(uint2*)(pbw + prow1 + pc1 + ph) = make_uint2(pk[1][2], pk[1][3]);              \
        *(uint2*)(pbw + prow1 + pc2 + ph) = make_uint2(pk[1][4], pk[1][5]);              \
        *(uint2*)(pbw + prow1 + pc3 + ph) = make_uint2(pk[1][6], pk[1][7]);              \
        asm volatile("" ::: "memory");                                                   \
        bf16x8s pa[2][2];                                                                \
        pa[0][0] = *(const bf16x8s*)(pbw + prow0 + pr0);                                 \
        pa[0][1] = *(const bf16x8s*)(pbw + prow0 + pr1);                                 \
        pa[1][0] = *(const bf16x8s*)(pbw + prow1 + pr0);                                 \
        pa[1][1] = *(const bf16x8s*)(pbw + prow1 + pr1);                                 \
        asm volatile("" ::: "memory");                                                   \
        __builtin_amdgcn_s_setprio(1);                                                   \
        _Pragma("unroll")                                                                \
        for (int hh = 0; hh < 2; ++hh)                                                   \
            _Pragma("unroll")                                                            \
            for (int g = 0; g < 2; ++g) {                                                \
                _Pragma("unroll")                                                        \
                for (int nf = 0; nf < 4; ++nf)                                           \
                    O[g][nf] = __builtin_amdgcn_mfma_f32_16x16x32_bf16(                  \
                        pa[g][hh], vf[hh][nf], O[g][nf], 0, 0, 0);                       \
                LS[g] = __builtin_amdgcn_mfma_f32_16x16x32_bf16(                         \
                    pa[g][hh], onesf, LS[g], 0, 0, 0);                                   \
            }                                                                            \
        __builtin_amdgcn_s_setprio(0);                                                   \
    } while (0)

    STAGE(0, 0);
    asm volatile("s_waitcnt vmcnt(0)" ::: "memory");
    __builtin_amdgcn_sched_barrier(0);
    __builtin_amdgcn_s_barrier();

    for (int t = 0; t < NT128; ++t) {
        int cur = t & 1;
        if (t + 1 < NT128) STAGE(cur ^ 1, (t + 1) * 128);

        const unsigned short* Kbuf = Ks[cur];
        const unsigned short* Vbuf = Vs[cur];

        #pragma unroll
        for (int hh2 = 0; hh2 < 2; ++hh2) {
            int kvh = t * 128 + hh2 * 64;
            if (kvh <= q0B + 31)
                BODY(qfB, oB, lsB, q0B, qa0B, qa1B, kvh, hh2, Kbuf, Vbuf);
            if (kvh <= q0A + 31)
                BODY(qfA, oA, lsA, q0A, qa0A, qa1A, kvh, hh2, Kbuf, Vbuf);
        }

        asm volatile("s_waitcnt vmcnt(0)" ::: "memory");
        __builtin_amdgcn_sched_barrier(0);
        __builtin_amdgcn_s_barrier();
    }

    // epilogue: both q-tiles
    #pragma unroll
    for (int r = 0; r < 4; ++r) {
        float liA0 = 1.0f / lsA[0][r], liA1 = 1.0f / lsA[1][r];
        float liB0 = 1.0f / lsB[0][r], liB1 = 1.0f / lsB[1][r];
        #pragma unroll
        for (int nf = 0; nf < 4; ++nf) {
            int col = hd * 64 + nf * 16 + l15;
            int rowA = q0A + l4 * 4 + r;
            int rowB = q0B + l4 * 4 + r;
            ctx[((size_t)b * 2048 + rowA) * 1024 + col]      = f2bf(oA[0][nf][r] * liA0);
            ctx[((size_t)b * 2048 + rowA + 16) * 1024 + col] = f2bf(oA[1][nf][r] * liA1);
            ctx[((size_t)b * 2048 + rowB) * 1024 + col]      = f2bf(oB[0][nf][r] * liB0);
            ctx[((size_t)b * 2048 + rowB + 16) * 1024 + col] = f2bf(oB[1][nf][r] * liB1);
        }
    }
#undef STAGE
#undef BODY
}

extern "C" void kernel_launch(void* const* d_in, const int* in_sizes, int n_in,
                              void* d_out, int out_size, void* d_ws, size_t ws_size,
                              hipStream_t stream) {
    const float* x      = (const float*)d_in[0];
    const float* W_attn = (const float*)d_in[1];
    const float* b_attn = (const float*)d_in[2];
    const float* W_proj = (const float*)d_in[3];
    const float* b_proj = (const float*)d_in[4];

    char* ws = (char*)d_ws;
    unsigned short* xb  = (unsigned short*)ws; ws += (size_t)8192 * 1024 * 2;
    unsigned short* wta = (unsigned short*)ws; ws += (size_t)3072 * 1024 * 2;
    unsigned short* wtp = (unsigned short*)ws; ws += (size_t)1024 * 1024 * 2;
    unsigned short* qkv = (unsigned short*)ws; ws += (size_t)8192 * 3072 * 2;
    unsigned short* vt  = (unsigned short*)ws; ws += (size_t)64 * 64 * 2048 * 2;
    unsigned short* ctx = (unsigned short*)ws;

    k_cvt_bf16<<<4096, 256, 0, stream>>>(x, xb, 8192 * 1024 / 8);
    k_transpose_w<<<16 * 48, 256, 0, stream>>>(W_attn, wta, 1024, 3072, QSCALE, 1024);
    k_transpose_w<<<16 * 16, 256, 0, stream>>>(W_proj, wtp, 1024, 1024, 1.0f, 0);
    k_gemm2b<1, 1, 1><<<768, 512, 0, stream>>>(xb, wta, b_attn, (void*)qkv, vt, 8192, 3072, 1024, 12);
    k_attn<<<512, 256, 0, stream>>>(qkv, vt, ctx);
    k_gemm2b<0, 0, 0><<<256, 512, 0, stream>>>(ctx, wtp, b_proj, d_out, nullptr, 8192, 1024, 1024, 4);
}